// Round 3
// baseline (448.254 us; speedup 1.0000x reference)
//
#include <hip/hip_runtime.h>
#include <hip/hip_fp16.h>

// Trilinear grid-sample, batch-pipelined two-phase:
//  transform(b): feats [b,F,D,H,W] f32 -> T(b) [D,H,W,F] fp16 (channels-last,
//                32 MiB/batch) — HBM-streaming bound.
//  gather(b):    per point, 4 (z,y) rows x 2x16B loads, f32 lerp — L3
//                random-line bound.
// The two phases use different memory subsystems, so stages 1..3 run
// transform(k) and gather(k-1) in the SAME launch on disjoint block ranges;
// stream order provides the T(b) dependency. Prologue/epilogue stages run
// one phase alone.

#define NB 4
#define NF 8
#define ND 128
#define NH 128
#define NW 128
#define HG 512
#define WG 512

#define SVOX ((size_t)ND * NH * NW)        // 2,097,152 voxels per batch
#define NPTS (HG * WG)                     // 262,144 points per batch

__device__ __forceinline__ void do_transform(
    const float* __restrict__ feats, __half* __restrict__ T,
    int b, int tid, int nthreads)
{
    const float* fb = feats + (size_t)b * NF * SVOX;
    const int nitems = (int)(SVOX / 4);            // 524,288 float4 groups

    for (int it = tid; it < nitems; it += nthreads) {
        size_t s4 = (size_t)it * 4;
        __half* tb = T + ((size_t)b * SVOX + s4) * NF;

        float4 vals[NF];
#pragma unroll
        for (int f = 0; f < NF; ++f)
            vals[f] = *(const float4*)(fb + (size_t)f * SVOX + s4);

#pragma unroll
        for (int i = 0; i < 4; ++i) {
            alignas(16) __half2 hv[4];
#pragma unroll
            for (int f = 0; f < 4; ++f) {
                float a = ((const float*)&vals[2 * f])[i];
                float c = ((const float*)&vals[2 * f + 1])[i];
                hv[f] = __floats2half2_rn(a, c);
            }
            *(uint4*)(tb + (size_t)i * NF) = *(const uint4*)hv;
        }
    }
}

__device__ __forceinline__ void row_accum(
    const __half* __restrict__ tb, size_t rowbase, bool hi,
    float wr, float um, float u, float acc[NF])
{
    uint4 lov = *(const uint4*)(tb + rowbase);        // [x0][f0..7]
    uint4 hiv = *(const uint4*)(tb + rowbase + NF);   // [x1][f0..7]
    uint4 c0 = hi ? hiv : lov;                        // x-edge clamp
    const uint4& c1 = hiv;

    const unsigned* p0 = (const unsigned*)&c0;
    const unsigned* p1 = (const unsigned*)&c1;
#pragma unroll
    for (int j = 0; j < 4; ++j) {
        unsigned u0 = p0[j], u1 = p1[j];
        float2 f0 = __half22float2(*(const __half2*)&u0);
        float2 f1 = __half22float2(*(const __half2*)&u1);
        acc[2 * j]     += wr * (um * f0.x + u * f1.x);
        acc[2 * j + 1] += wr * (um * f0.y + u * f1.y);
    }
}

__device__ __forceinline__ void do_gather(
    const __half* __restrict__ T, const float* __restrict__ grid,
    float* __restrict__ out, int b, int tid, int nthreads)
{
    for (int p = tid; p < NPTS; p += nthreads) {
        const float* g = grid + ((size_t)b * NPTS + p) * 3;
        float x = g[0], y = g[1], z = g[2];

        x = fminf(fmaxf(x, -1.0f), 1.0f);
        y = fminf(fmaxf(y, -1.0f), 1.0f);
        z = fminf(fmaxf(z, -1.0f), 1.0f);
        x = (x + 1.0f) * 0.5f * (float)(NW - 1);
        y = (y + 1.0f) * 0.5f * (float)(NH - 1);
        z = (z + 1.0f) * 0.5f * (float)(ND - 1);

        float xf = floorf(x), yf = floorf(y), zf = floorf(z);
        float u = x - xf, v = y - yf, w = z - zf;
        float um = 1.0f - u, vm = 1.0f - v, wm = 1.0f - w;

        int ix0 = min(max((int)xf, 0), NW - 1);
        int iy0 = min(max((int)yf, 0), NH - 1);
        int iy1 = min(iy0 + 1, NH - 1);
        int iz0 = min(max((int)zf, 0), ND - 1);
        int iz1 = min(iz0 + 1, ND - 1);

        int xb = min(ix0, NW - 2);
        bool hi = (ix0 != xb);

        const __half* tb = T + (size_t)b * SVOX * NF;
        size_t r00 = ((size_t)(iz0 * NH + iy0) * NW + xb) * NF;
        size_t r01 = ((size_t)(iz0 * NH + iy1) * NW + xb) * NF;
        size_t r10 = ((size_t)(iz1 * NH + iy0) * NW + xb) * NF;
        size_t r11 = ((size_t)(iz1 * NH + iy1) * NW + xb) * NF;

        float acc[NF];
#pragma unroll
        for (int f = 0; f < NF; ++f) acc[f] = 0.0f;

        row_accum(tb, r00, hi, wm * vm, um, u, acc);
        row_accum(tb, r01, hi, wm * v,  um, u, acc);
        row_accum(tb, r10, hi, w  * vm, um, u, acc);
        row_accum(tb, r11, hi, w  * v,  um, u, acc);

        float* o = out + (size_t)b * NF * NPTS + p;
#pragma unroll
        for (int f = 0; f < NF; ++f)
            o[(size_t)f * NPTS] = acc[f];
    }
}

// tb/gb: batch index to transform / gather, or -1 to skip.
// Blocks [0, splitA) take the transform role; [splitA, gridDim.x) gather.
__global__ __launch_bounds__(256) void stage_kernel(
    const float* __restrict__ feats, const float* __restrict__ grid,
    float* __restrict__ out, __half* __restrict__ T,
    int tb, int gb, int splitA)
{
    int blk = blockIdx.x;
    if (blk < splitA) {
        if (tb >= 0)
            do_transform(feats, T, tb, blk * 256 + (int)threadIdx.x, splitA * 256);
    } else {
        if (gb >= 0) {
            int nB = (int)gridDim.x - splitA;
            do_gather(T, grid, out, gb, (blk - splitA) * 256 + (int)threadIdx.x,
                      nB * 256);
        }
    }
}

// ---- fallback (round-1 kernel) if ws_size is too small ----
__global__ __launch_bounds__(256) void trilerp_f32_kernel(
    const float* __restrict__ feats,
    const float* __restrict__ grid,
    float* __restrict__ out)
{
    const int P = NPTS;
    int idx = blockIdx.x * blockDim.x + threadIdx.x;
    int b = idx >> 18;
    int p = idx & (P - 1);

    const float* g = grid + (size_t)idx * 3;
    float x = g[0], y = g[1], z = g[2];
    x = fminf(fmaxf(x, -1.0f), 1.0f);
    y = fminf(fmaxf(y, -1.0f), 1.0f);
    z = fminf(fmaxf(z, -1.0f), 1.0f);
    x = (x + 1.0f) * 0.5f * (float)(NW - 1);
    y = (y + 1.0f) * 0.5f * (float)(NH - 1);
    z = (z + 1.0f) * 0.5f * (float)(ND - 1);

    float xf = floorf(x), yf = floorf(y), zf = floorf(z);
    float u = x - xf, v = y - yf, w = z - zf;

    int ix0 = min(max((int)xf, 0), NW - 1);
    int ix1 = min(ix0 + 1, NW - 1);
    int iy0 = min(max((int)yf, 0), NH - 1);
    int iy1 = min(iy0 + 1, NH - 1);
    int iz0 = min(max((int)zf, 0), ND - 1);
    int iz1 = min(iz0 + 1, ND - 1);

    float um = 1.0f - u, vm = 1.0f - v, wm = 1.0f - w;
    float w000 = um * vm * wm, w100 = u * vm * wm;
    float w010 = um * v * wm,  w110 = u * v * wm;
    float w001 = um * vm * w,  w101 = u * vm * w;
    float w011 = um * v * w,   w111 = u * v * w;

    int off00 = (iz0 * NH + iy0) * NW;
    int off01 = (iz0 * NH + iy1) * NW;
    int off10 = (iz1 * NH + iy0) * NW;
    int off11 = (iz1 * NH + iy1) * NW;

    const float* fb = feats + (size_t)b * NF * SVOX;
    float* o = out + (size_t)b * NF * P + p;

#pragma unroll
    for (int f = 0; f < NF; ++f) {
        const float* fp = fb + (size_t)f * SVOX;
        float r = w000 * fp[off00 + ix0] + w100 * fp[off00 + ix1]
                + w010 * fp[off01 + ix0] + w110 * fp[off01 + ix1]
                + w001 * fp[off10 + ix0] + w101 * fp[off10 + ix1]
                + w011 * fp[off11 + ix0] + w111 * fp[off11 + ix1];
        o[(size_t)f * P] = r;
    }
}

extern "C" void kernel_launch(void* const* d_in, const int* in_sizes, int n_in,
                              void* d_out, int out_size, void* d_ws, size_t ws_size,
                              hipStream_t stream) {
    const float* feats = (const float*)d_in[0];
    const float* grid  = (const float*)d_in[1];
    float* out = (float*)d_out;

    const size_t needed = (size_t)NB * SVOX * NF * sizeof(__half); // 128 MiB

    if (ws_size >= needed) {
        __half* T = (__half*)d_ws;
        const int NBLK = 2048;                    // 8 blocks/CU
        dim3 block(256);
        // Stage 0: transform batch 0 on the whole machine.
        stage_kernel<<<NBLK, block, 0, stream>>>(feats, grid, out, T, 0, -1, NBLK);
        // Stages 1..3: transform(k) || gather(k-1), half the blocks each.
        for (int k = 1; k < NB; ++k)
            stage_kernel<<<NBLK, block, 0, stream>>>(feats, grid, out, T, k, k - 1,
                                                     NBLK / 2);
        // Stage 4: gather batch 3 on the whole machine.
        stage_kernel<<<NBLK, block, 0, stream>>>(feats, grid, out, T, -1, NB - 1, 0);
    } else {
        const int total = NB * HG * WG;
        trilerp_f32_kernel<<<total / 256, 256, 0, stream>>>(feats, grid, out);
    }
}